// Round 3
// baseline (166.027 us; speedup 1.0000x reference)
//
#include <hip/hip_runtime.h>

// PrototypicalNetwork: out[q,c] = -1/8 * sum_b sqrt(max(q2[q] + p2[b,c] - 2*qp[b,q,c], 0))
// bf16 MFMA 16x16x32 for the qp GEMM (M=65536, N=1024, K=128).
// R3: L1-BW diet. Wave = 4 m-tiles x 2 c-tiles (B-frag reused 4x from regs;
// pfrag loads/wave 256 -> 64). A-frags staged via LDS once per block.
// Distance algebra folded into MFMA: pfrag holds bf16(-proto/32), p2 holds
// |p|^2/64, q2 scaled 1/64, accumulator initialized to q2'+p2' so the MFMA
// result IS d^2/64 -> sqrt gives d/8; store negated sum. Saves the per-element
// fma and final scale. Plain stores (NT stores inflated WRITE_SIZE 34% in R2).

#define DIM   128
#define NCLS  128
#define SHOTS 32
#define NB    8
#define NQ    65536

using short8 = __attribute__((ext_vector_type(8))) short;
using f32x4  = __attribute__((ext_vector_type(4))) float;

__device__ __forceinline__ unsigned short f2bf(float x) {
  union { float f; unsigned u; } v; v.f = x;
  unsigned r = v.u + 0x7fffu + ((v.u >> 16) & 1u);   // round-to-nearest-even
  return (unsigned short)(r >> 16);
}

// ---------------------------------------------------------------------------
// Kernel 1: bootstrap-mean protos -> bf16(-proto/32) in MFMA B-frag-major
// layout, plus p2[b,c] = |proto|^2 / 64 (fp32).
// B-frag layout (16x16x32): lane holds B[n=lane&15][k=(lane>>4)*8+j].
// Slot = (b*8+ct)*4+kiter; one slot = 64 lanes * 16 B = 1 KB contiguous.
// ---------------------------------------------------------------------------
__global__ __launch_bounds__(128) void proto_kernel(
    const float* __restrict__ sup, const int* __restrict__ bidx,
    unsigned short* __restrict__ pfrag, float* __restrict__ p2) {
  int bc = blockIdx.x;            // b*128 + c
  int c  = bc & (NCLS - 1);
  int d  = threadIdx.x;           // 0..127 = feature dim
  __shared__ int   sidx[SHOTS];
  __shared__ float wsum[2];
  if (d < SHOTS) sidx[d] = bidx[bc * SHOTS + d];
  __syncthreads();
  float acc = 0.f;
  const float* base = sup + c * SHOTS * DIM + d;
  #pragma unroll
  for (int s = 0; s < SHOTS; ++s) acc += base[sidx[s] * DIM];
  float proto = acc * (1.0f / 32.0f);

  int b     = bc >> 7;
  int ct    = c >> 4, l15c = c & 15;
  int kiter = d >> 5, quad = (d >> 3) & 3, j = d & 7;
  int lane  = l15c + (quad << 4);
  int slot  = (b * 8 + ct) * 4 + kiter;
  pfrag[slot * 512 + lane * 8 + j] = f2bf(proto * -0.03125f);  // -proto/32

  float sq = proto * proto;
  #pragma unroll
  for (int off = 32; off > 0; off >>= 1) sq += __shfl_down(sq, off, 64);
  if ((d & 63) == 0) wsum[d >> 6] = sq;
  __syncthreads();
  if (d == 0) p2[bc] = (wsum[0] + wsum[1]) * (1.0f / 64.0f);
}

// ---------------------------------------------------------------------------
// Kernel 2: block = 64 query rows x 128 classes, 4 waves.
// wave w owns ALL 4 m-tiles (64 rows) and c-tiles {2w, 2w+1}.
// A-frags staged to LDS once (each wave stages 16 rows), then every wave
// holds all 16 A-frags (4mt x 4k) in registers for the whole b-loop.
// ---------------------------------------------------------------------------
__global__ __launch_bounds__(256) void dist_kernel(
    const float* __restrict__ q, const uint4* __restrict__ pfrag,
    const float* __restrict__ p2, float* __restrict__ out) {
  int tid  = threadIdx.x;
  int w    = tid >> 6, lane = tid & 63;
  int l15  = lane & 15, quad = lane >> 4;
  int q0   = blockIdx.x << 6;

  __shared__ unsigned short aflds[16 * 64 * 8];  // [slot=mt*4+k][lane][8] bf16
  __shared__ float q2s[64];                      // |q|^2 / 64 per row

  // --- stage: wave w converts rows [16w, 16w+16) to A-frag layout in LDS ---
  // A-layout: lane (l15,quad) of m-tile mt, k-iter i holds
  // A[m=l15][k = i*32 + quad*8 + j], j=0..7 -> 8 consecutive floats.
  {
    int row = w * 16 + l15;
    const float* qr = q + (size_t)(q0 + row) * DIM + quad * 8;
    float s = 0.f;
    #pragma unroll
    for (int i = 0; i < 4; ++i) {
      float4 x0 = *reinterpret_cast<const float4*>(qr + i * 32);
      float4 x1 = *reinterpret_cast<const float4*>(qr + i * 32 + 4);
      s += x0.x*x0.x + x0.y*x0.y + x0.z*x0.z + x0.w*x0.w
         + x1.x*x1.x + x1.y*x1.y + x1.z*x1.z + x1.w*x1.w;
      short8 a;
      a[0] = (short)f2bf(x0.x); a[1] = (short)f2bf(x0.y);
      a[2] = (short)f2bf(x0.z); a[3] = (short)f2bf(x0.w);
      a[4] = (short)f2bf(x1.x); a[5] = (short)f2bf(x1.y);
      a[6] = (short)f2bf(x1.z); a[7] = (short)f2bf(x1.w);
      *reinterpret_cast<short8*>(&aflds[((w * 4 + i) * 64 + lane) * 8]) = a;
    }
    s += __shfl_xor(s, 16, 64);     // reduce across the 4 quads of this row
    s += __shfl_xor(s, 32, 64);
    if (quad == 0) q2s[row] = s * (1.0f / 64.0f);
  }
  __syncthreads();

  // --- every wave pulls all 16 A-frags + per-row q2' into registers ---
  short8 af[4][4];
  #pragma unroll
  for (int mt = 0; mt < 4; ++mt)
    #pragma unroll
    for (int k = 0; k < 4; ++k)
      af[mt][k] = *reinterpret_cast<const short8*>(
          &aflds[((mt * 4 + k) * 64 + lane) * 8]);

  f32x4 q2r[4];                     // q2' for C/D rows quad*4 + r of m-tile mt
  #pragma unroll
  for (int mt = 0; mt < 4; ++mt) {
    float4 v = *reinterpret_cast<const float4*>(&q2s[mt * 16 + quad * 4]);
    q2r[mt][0] = v.x; q2r[mt][1] = v.y; q2r[mt][2] = v.z; q2r[mt][3] = v.w;
  }

  // p2' for this wave's two c-tiles, all b, hoisted (L2-hot, 16 dwords)
  float p2v[NB][2];
  #pragma unroll
  for (int b = 0; b < NB; ++b)
    #pragma unroll
    for (int jj = 0; jj < 2; ++jj)
      p2v[b][jj] = p2[b * NCLS + (w * 2 + jj) * 16 + l15];

  f32x4 oacc[4][2];
  #pragma unroll
  for (int mt = 0; mt < 4; ++mt)
    #pragma unroll
    for (int jj = 0; jj < 2; ++jj)
      oacc[mt][jj] = (f32x4){0.f, 0.f, 0.f, 0.f};

  // --- main loop: fully unrolled straight line; scheduler hoists loads ---
  #pragma unroll
  for (int b = 0; b < NB; ++b) {
    #pragma unroll
    for (int jj = 0; jj < 2; ++jj) {
      int ct = w * 2 + jj;
      const uint4* bp = pfrag + (size_t)((b * 8 + ct) * 4) * 64 + lane;
      uint4 f0 = bp[0], f1 = bp[64], f2 = bp[128], f3 = bp[192];
      short8 b0 = __builtin_bit_cast(short8, f0);
      short8 b1 = __builtin_bit_cast(short8, f1);
      short8 b2 = __builtin_bit_cast(short8, f2);
      short8 b3 = __builtin_bit_cast(short8, f3);

      f32x4 qp[4];
      #pragma unroll
      for (int mt = 0; mt < 4; ++mt) {   // C-init = q2' + p2'
        f32x4 t;
        #pragma unroll
        for (int r = 0; r < 4; ++r) t[r] = q2r[mt][r] + p2v[b][jj];
        qp[mt] = t;
      }
      #pragma unroll
      for (int mt = 0; mt < 4; ++mt)
        qp[mt] = __builtin_amdgcn_mfma_f32_16x16x32_bf16(af[mt][0], b0, qp[mt], 0, 0, 0);
      #pragma unroll
      for (int mt = 0; mt < 4; ++mt)
        qp[mt] = __builtin_amdgcn_mfma_f32_16x16x32_bf16(af[mt][1], b1, qp[mt], 0, 0, 0);
      #pragma unroll
      for (int mt = 0; mt < 4; ++mt)
        qp[mt] = __builtin_amdgcn_mfma_f32_16x16x32_bf16(af[mt][2], b2, qp[mt], 0, 0, 0);
      #pragma unroll
      for (int mt = 0; mt < 4; ++mt)
        qp[mt] = __builtin_amdgcn_mfma_f32_16x16x32_bf16(af[mt][3], b3, qp[mt], 0, 0, 0);

      #pragma unroll
      for (int mt = 0; mt < 4; ++mt)
        #pragma unroll
        for (int r = 0; r < 4; ++r)       // qp = d^2/64; sqrt -> d/8
          oacc[mt][jj][r] += __builtin_sqrtf(fmaxf(qp[mt][r], 0.0f));
    }
  }

  // --- store: row = q0 + mt*16 + quad*4 + r, col = (2w+jj)*16 + l15 ---
  #pragma unroll
  for (int mt = 0; mt < 4; ++mt)
    #pragma unroll
    for (int jj = 0; jj < 2; ++jj) {
      int col = (w * 2 + jj) * 16 + l15;
      #pragma unroll
      for (int r = 0; r < 4; ++r) {
        int row = q0 + mt * 16 + quad * 4 + r;
        out[(size_t)row * NCLS + col] = -oacc[mt][jj][r];
      }
    }
}

extern "C" void kernel_launch(void* const* d_in, const int* in_sizes, int n_in,
                              void* d_out, int out_size, void* d_ws, size_t ws_size,
                              hipStream_t stream) {
  const float* sup   = (const float*)d_in[0];   // [4096,128] f32
  // d_in[1] = support_labels (unused: sorted/balanced by construction)
  const float* query = (const float*)d_in[2];   // [65536,128] f32
  const int*   bidx  = (const int*)d_in[3];     // [8,128,32] i32
  float* out = (float*)d_out;                   // [65536,128] f32

  unsigned short* pfrag = (unsigned short*)d_ws;              // 256 KB bf16 frags
  float* p2 = (float*)((char*)d_ws + (size_t)NB * NCLS * DIM * 2); // 4 KB

  proto_kernel<<<NB * NCLS, 128, 0, stream>>>(sup, bidx, pfrag, p2);
  dist_kernel<<<NQ / 64, 256, 0, stream>>>(query, (const uint4*)pfrag, p2, out);
}

// Round 4
// 140.654 us; speedup vs baseline: 1.1804x; 1.1804x over previous
//
#include <hip/hip_runtime.h>

// PrototypicalNetwork: out[q,c] = -1/8 * sum_b sqrt(max(q2[q] + p2[b,c] - 2*qp[b,q,c], 0))
// bf16 MFMA 16x16x32 for qp GEMM (M=65536, N=1024, K=128).
// R4: TLP fix. 64x64 blocks (grid 2048 = 8 blocks/CU of work), wave = 2mt x 2ct,
// ~100 VGPR -> ~20 resident waves/CU (R1 had 16 max, 6.7 avg). Raw v_sqrt_f32
// (R3 accidentally used the IEEE-expanded sqrt -> VALU blowup). Distance algebra
// folded into the MFMA accumulator: pfrag = bf16(-proto/32), p2' = |p|^2/64,
// q2' = |q|^2/64, C-init = q2'+p2' so MFMA emits d^2/64; sqrt -> d/8.

#define DIM   128
#define NCLS  128
#define SHOTS 32
#define NB    8
#define NQ    65536

using short8 = __attribute__((ext_vector_type(8))) short;
using f32x4  = __attribute__((ext_vector_type(4))) float;

__device__ __forceinline__ unsigned short f2bf(float x) {
  union { float f; unsigned u; } v; v.f = x;
  unsigned r = v.u + 0x7fffu + ((v.u >> 16) & 1u);   // round-to-nearest-even
  return (unsigned short)(r >> 16);
}

__device__ __forceinline__ float fast_sqrt(float x) {
#if __has_builtin(__builtin_amdgcn_sqrtf)
  return __builtin_amdgcn_sqrtf(x);   // raw v_sqrt_f32 — rel err ~1e-6, fine vs 0.31 abs threshold
#else
  return sqrtf(x);
#endif
}

// ---------------------------------------------------------------------------
// Kernel 1: bootstrap-mean protos -> bf16(-proto/32) in MFMA B-frag-major
// layout, plus p2[b,c] = |proto|^2 / 64 (fp32).
// B-frag layout (16x16x32): lane holds B[n=lane&15][k=(lane>>4)*8+j].
// Slot = (b*8+ct)*4+kiter; one slot = 64 lanes * 16 B = 1 KB contiguous.
// ---------------------------------------------------------------------------
__global__ __launch_bounds__(128) void proto_kernel(
    const float* __restrict__ sup, const int* __restrict__ bidx,
    unsigned short* __restrict__ pfrag, float* __restrict__ p2) {
  int bc = blockIdx.x;            // b*128 + c
  int c  = bc & (NCLS - 1);
  int d  = threadIdx.x;           // 0..127 = feature dim
  __shared__ int   sidx[SHOTS];
  __shared__ float wsum[2];
  if (d < SHOTS) sidx[d] = bidx[bc * SHOTS + d];
  __syncthreads();
  float acc = 0.f;
  const float* base = sup + c * SHOTS * DIM + d;
  #pragma unroll
  for (int s = 0; s < SHOTS; ++s) acc += base[sidx[s] * DIM];
  float proto = acc * (1.0f / 32.0f);

  int b     = bc >> 7;
  int ct    = c >> 4, l15c = c & 15;
  int kiter = d >> 5, quad = (d >> 3) & 3, j = d & 7;
  int lane  = l15c + (quad << 4);
  int slot  = (b * 8 + ct) * 4 + kiter;
  pfrag[slot * 512 + lane * 8 + j] = f2bf(proto * -0.03125f);  // -proto/32

  float sq = proto * proto;
  #pragma unroll
  for (int off = 32; off > 0; off >>= 1) sq += __shfl_down(sq, off, 64);
  if ((d & 63) == 0) wsum[d >> 6] = sq;
  __syncthreads();
  if (d == 0) p2[bc] = (wsum[0] + wsum[1]) * (1.0f / 64.0f);
}

// ---------------------------------------------------------------------------
// Kernel 2: block = 64 query rows x 64 classes, 4 waves, grid 2048.
// blockIdx: bit0 = column half (c-tiles 0-3 or 4-7), rest = 64-row chunk.
// Wave w: mtg=w&1 (rows mtg*32..), ctg=w>>1 (2 c-tiles). ~100 VGPR target.
// ---------------------------------------------------------------------------
__global__ __launch_bounds__(256) void dist_kernel(
    const float* __restrict__ q, const uint4* __restrict__ pfrag,
    const float* __restrict__ p2, float* __restrict__ out) {
  int tid  = threadIdx.x;
  int w    = tid >> 6, lane = tid & 63;
  int l15  = lane & 15, quad = lane >> 4;
  int mtg  = w & 1, ctg = w >> 1;
  int q0   = (blockIdx.x >> 1) << 6;
  int cb   = (blockIdx.x & 1) << 2;   // base c-tile (0 or 4)

  __shared__ float q2p[64][4];        // per-row, per-quad partial |q|^2

  // --- A-fragments (Q) straight from global in fragment layout ---
  // A-layout: lane (l15,quad) holds A[m=l15][k=i*32+quad*8+j], 8 consec floats.
  short8 af[2][4];
  #pragma unroll
  for (int mt2 = 0; mt2 < 2; ++mt2) {
    int rrow = mtg * 32 + mt2 * 16 + l15;
    const float* qr = q + (size_t)(q0 + rrow) * DIM + quad * 8;
    float s = 0.f;
    #pragma unroll
    for (int k = 0; k < 4; ++k) {
      float4 x0 = *reinterpret_cast<const float4*>(qr + k * 32);
      float4 x1 = *reinterpret_cast<const float4*>(qr + k * 32 + 4);
      s += x0.x*x0.x + x0.y*x0.y + x0.z*x0.z + x0.w*x0.w
         + x1.x*x1.x + x1.y*x1.y + x1.z*x1.z + x1.w*x1.w;
      short8 a;
      a[0] = (short)f2bf(x0.x); a[1] = (short)f2bf(x0.y);
      a[2] = (short)f2bf(x0.z); a[3] = (short)f2bf(x0.w);
      a[4] = (short)f2bf(x1.x); a[5] = (short)f2bf(x1.y);
      a[6] = (short)f2bf(x1.z); a[7] = (short)f2bf(x1.w);
      af[mt2][k] = a;
    }
    if (ctg == 0) q2p[rrow][quad] = s;   // one writer per (row,quad)
  }
  __syncthreads();

  // q2' per accumulator row (C/D row = quad*4 + r within m-tile), scaled 1/64
  f32x4 q2r[2];
  #pragma unroll
  for (int mt2 = 0; mt2 < 2; ++mt2) {
    int r0 = mtg * 32 + mt2 * 16 + quad * 4;
    #pragma unroll
    for (int r = 0; r < 4; ++r) {
      float4 pp = *reinterpret_cast<const float4*>(&q2p[r0 + r][0]);
      q2r[mt2][r] = (pp.x + pp.y + pp.z + pp.w) * (1.0f / 64.0f);
    }
  }

  f32x4 oacc[2][2];
  #pragma unroll
  for (int i = 0; i < 2; ++i)
    #pragma unroll
    for (int jj = 0; jj < 2; ++jj)
      oacc[i][jj] = (f32x4){0.f, 0.f, 0.f, 0.f};

  // --- b-loop: fully unrolled; scheduler hoists next-b loads over epilogue ---
  #pragma unroll
  for (int b = 0; b < NB; ++b) {
    uint4 f[2][4];
    float p2v[2];
    #pragma unroll
    for (int ct2 = 0; ct2 < 2; ++ct2) {
      int ct = cb + ctg * 2 + ct2;
      const uint4* bp = pfrag + (size_t)((b * 8 + ct) * 4) * 64 + lane;
      #pragma unroll
      for (int k = 0; k < 4; ++k) f[ct2][k] = bp[k * 64];
      p2v[ct2] = p2[b * NCLS + ct * 16 + l15];
    }

    f32x4 qp[2][2];
    #pragma unroll
    for (int mt2 = 0; mt2 < 2; ++mt2)       // C-init = q2' + p2'
      #pragma unroll
      for (int ct2 = 0; ct2 < 2; ++ct2)
        #pragma unroll
        for (int r = 0; r < 4; ++r)
          qp[mt2][ct2][r] = q2r[mt2][r] + p2v[ct2];

    #pragma unroll
    for (int k = 0; k < 4; ++k)
      #pragma unroll
      for (int ct2 = 0; ct2 < 2; ++ct2) {
        short8 bfk = __builtin_bit_cast(short8, f[ct2][k]);
        #pragma unroll
        for (int mt2 = 0; mt2 < 2; ++mt2)
          qp[mt2][ct2] = __builtin_amdgcn_mfma_f32_16x16x32_bf16(
              af[mt2][k], bfk, qp[mt2][ct2], 0, 0, 0);
      }

    #pragma unroll
    for (int mt2 = 0; mt2 < 2; ++mt2)
      #pragma unroll
      for (int ct2 = 0; ct2 < 2; ++ct2)
        #pragma unroll
        for (int r = 0; r < 4; ++r)          // qp = d^2/64 -> sqrt = d/8
          oacc[mt2][ct2][r] += fast_sqrt(fmaxf(qp[mt2][ct2][r], 0.0f));
  }

  // --- store: row = q0 + mtg*32 + mt2*16 + quad*4 + r, col = ct*16 + l15 ---
  #pragma unroll
  for (int mt2 = 0; mt2 < 2; ++mt2)
    #pragma unroll
    for (int ct2 = 0; ct2 < 2; ++ct2) {
      int col = (cb + ctg * 2 + ct2) * 16 + l15;
      #pragma unroll
      for (int r = 0; r < 4; ++r) {
        int row = q0 + mtg * 32 + mt2 * 16 + quad * 4 + r;
        out[(size_t)row * NCLS + col] = -oacc[mt2][ct2][r];
      }
    }
}

extern "C" void kernel_launch(void* const* d_in, const int* in_sizes, int n_in,
                              void* d_out, int out_size, void* d_ws, size_t ws_size,
                              hipStream_t stream) {
  const float* sup   = (const float*)d_in[0];   // [4096,128] f32
  // d_in[1] = support_labels (unused: sorted/balanced by construction)
  const float* query = (const float*)d_in[2];   // [65536,128] f32
  const int*   bidx  = (const int*)d_in[3];     // [8,128,32] i32
  float* out = (float*)d_out;                   // [65536,128] f32

  unsigned short* pfrag = (unsigned short*)d_ws;              // 256 KB bf16 frags
  float* p2 = (float*)((char*)d_ws + (size_t)NB * NCLS * DIM * 2); // 4 KB

  proto_kernel<<<NB * NCLS, 128, 0, stream>>>(sup, bidx, pfrag, p2);
  dist_kernel<<<(NQ / 64) * 2, 256, 0, stream>>>(query, (const uint4*)pfrag, p2, out);
}

// Round 5
// 121.220 us; speedup vs baseline: 1.3696x; 1.1603x over previous
//
#include <hip/hip_runtime.h>

// PrototypicalNetwork: out[q,c] = -1/8 * sum_b sqrt(max(q2[q] + p2[b,c] - 2*qp[b,q,c], 0))
// bf16 MFMA 16x16x32 for qp GEMM (M=65536, N=1024, K=128).
// R5: TLP without R4's confounds. 32x128 blocks (grid 2048, query read ONCE),
// wave = 2mt x 2ct disjoint, zero LDS (q2 via bpermute shuffles), b-loop
// unroll-1 with X/Y full-b prefetch ping-pong, VGPR budget ~124 (4 waves/SIMD).
// Algebra folded into MFMA: pfrag = bf16(-proto/32), p2' = |p|^2/64,
// q2' = |q|^2/64, C-init = q2'+p2' so MFMA emits d^2/64; raw v_sqrt -> d/8.

#define DIM   128
#define NCLS  128
#define SHOTS 32
#define NB    8
#define NQ    65536

using short8 = __attribute__((ext_vector_type(8))) short;
using f32x4  = __attribute__((ext_vector_type(4))) float;

__device__ __forceinline__ unsigned short f2bf(float x) {
  union { float f; unsigned u; } v; v.f = x;
  unsigned r = v.u + 0x7fffu + ((v.u >> 16) & 1u);   // round-to-nearest-even
  return (unsigned short)(r >> 16);
}

__device__ __forceinline__ float fast_sqrt(float x) {
#if __has_builtin(__builtin_amdgcn_sqrtf)
  return __builtin_amdgcn_sqrtf(x);   // raw v_sqrt_f32 (R3 regression: never use IEEE sqrtf here)
#else
  return sqrtf(x);
#endif
}

// ---------------------------------------------------------------------------
// Kernel 1: bootstrap-mean protos -> bf16(-proto/32) in MFMA B-frag-major
// layout, plus p2[b,c] = |proto|^2 / 64 (fp32).
// B-frag layout (16x16x32): lane holds B[n=lane&15][k=(lane>>4)*8+j].
// Slot = (b*8+ct)*4+kiter; one slot = 64 lanes * 16 B = 1 KB contiguous.
// ---------------------------------------------------------------------------
__global__ __launch_bounds__(128) void proto_kernel(
    const float* __restrict__ sup, const int* __restrict__ bidx,
    unsigned short* __restrict__ pfrag, float* __restrict__ p2) {
  int bc = blockIdx.x;            // b*128 + c
  int c  = bc & (NCLS - 1);
  int d  = threadIdx.x;           // 0..127 = feature dim
  __shared__ int   sidx[SHOTS];
  __shared__ float wsum[2];
  if (d < SHOTS) sidx[d] = bidx[bc * SHOTS + d];
  __syncthreads();
  float acc = 0.f;
  const float* base = sup + c * SHOTS * DIM + d;
  #pragma unroll
  for (int s = 0; s < SHOTS; ++s) acc += base[sidx[s] * DIM];
  float proto = acc * (1.0f / 32.0f);

  int b     = bc >> 7;
  int ct    = c >> 4, l15c = c & 15;
  int kiter = d >> 5, quad = (d >> 3) & 3, j = d & 7;
  int lane  = l15c + (quad << 4);
  int slot  = (b * 8 + ct) * 4 + kiter;
  pfrag[slot * 512 + lane * 8 + j] = f2bf(proto * -0.03125f);  // -proto/32

  float sq = proto * proto;
  #pragma unroll
  for (int off = 32; off > 0; off >>= 1) sq += __shfl_down(sq, off, 64);
  if ((d & 63) == 0) wsum[d >> 6] = sq;
  __syncthreads();
  if (d == 0) p2[bc] = (wsum[0] + wsum[1]) * (1.0f / 64.0f);
}

// ---------------------------------------------------------------------------
// Kernel 2: block = 32 query rows x 128 classes, 4 waves, grid 2048.
// Wave w owns both m-tiles (rows q0..q0+31) and c-tiles {2w, 2w+1}.
// No LDS, no barriers. b-loop: X/Y register ping-pong prefetch.
// ---------------------------------------------------------------------------
__global__ __launch_bounds__(256) void dist_kernel(
    const float* __restrict__ q, const uint4* __restrict__ pfrag,
    const float* __restrict__ p2, float* __restrict__ out) {
  int tid  = threadIdx.x;
  int w    = tid >> 6, lane = tid & 63;
  int l15  = lane & 15, quad = lane >> 4;
  int q0   = blockIdx.x << 5;

  // --- A-fragments straight from global in fragment layout; q2 via shuffle ---
  // A-layout: lane (l15,quad) holds A[m=l15][k=i*32+quad*8+j], 8 consec floats.
  short8 af[2][4];
  float  q2row[2];                  // this lane's row (l15) |q|^2/64, per m-tile
  #pragma unroll
  for (int mt2 = 0; mt2 < 2; ++mt2) {
    int row = q0 + mt2 * 16 + l15;
    const float* qr = q + (size_t)row * DIM + quad * 8;
    float s = 0.f;
    #pragma unroll
    for (int k = 0; k < 4; ++k) {
      float4 x0 = *reinterpret_cast<const float4*>(qr + k * 32);
      float4 x1 = *reinterpret_cast<const float4*>(qr + k * 32 + 4);
      s += x0.x*x0.x + x0.y*x0.y + x0.z*x0.z + x0.w*x0.w
         + x1.x*x1.x + x1.y*x1.y + x1.z*x1.z + x1.w*x1.w;
      short8 a;
      a[0] = (short)f2bf(x0.x); a[1] = (short)f2bf(x0.y);
      a[2] = (short)f2bf(x0.z); a[3] = (short)f2bf(x0.w);
      a[4] = (short)f2bf(x1.x); a[5] = (short)f2bf(x1.y);
      a[6] = (short)f2bf(x1.z); a[7] = (short)f2bf(x1.w);
      af[mt2][k] = a;
    }
    s += __shfl_xor(s, 16, 64);     // row total across the 4 quad k-slices
    s += __shfl_xor(s, 32, 64);
    q2row[mt2] = s * (1.0f / 64.0f);
  }

  // q2' per C/D accumulator slot: C row = quad*4 + r -> pull from lane quad*4+r
  f32x4 q2r[2];
  #pragma unroll
  for (int mt2 = 0; mt2 < 2; ++mt2)
    #pragma unroll
    for (int r = 0; r < 4; ++r)
      q2r[mt2][r] = __shfl(q2row[mt2], quad * 4 + r, 64);

  // p2' hoisted for this wave's two c-tiles, all b (16 L2-hot dwords)
  float p2v[NB][2];
  #pragma unroll
  for (int b = 0; b < NB; ++b)
    #pragma unroll
    for (int jj = 0; jj < 2; ++jj)
      p2v[b][jj] = p2[b * NCLS + (w * 2 + jj) * 16 + l15];

  f32x4 oacc[2][2];
  #pragma unroll
  for (int i = 0; i < 2; ++i)
    #pragma unroll
    for (int jj = 0; jj < 2; ++jj)
      oacc[i][jj] = (f32x4){0.f, 0.f, 0.f, 0.f};

  // --- b-loop: X/Y ping-pong, 8 frag loads in flight across each compute ---
  uint4 bufX[8], bufY[8];

  #define LOAD_B(BUF, B)                                                      \
    {                                                                         \
      _Pragma("unroll")                                                       \
      for (int jj = 0; jj < 2; ++jj) {                                        \
        int ct = w * 2 + jj;                                                  \
        const uint4* bp = pfrag + (size_t)(((B) * 8 + ct) * 4) * 64 + lane;   \
        _Pragma("unroll")                                                     \
        for (int k = 0; k < 4; ++k) BUF[jj * 4 + k] = bp[k * 64];             \
      }                                                                       \
    }

  #define COMPUTE_B(BUF, B)                                                   \
    {                                                                         \
      _Pragma("unroll")                                                       \
      for (int jj = 0; jj < 2; ++jj) {                                        \
        f32x4 qp0, qp1;                                                       \
        _Pragma("unroll")                                                     \
        for (int r = 0; r < 4; ++r) {                                         \
          qp0[r] = q2r[0][r] + p2v[B][jj];                                    \
          qp1[r] = q2r[1][r] + p2v[B][jj];                                    \
        }                                                                     \
        _Pragma("unroll")                                                     \
        for (int k = 0; k < 4; ++k) {                                         \
          short8 bfk = __builtin_bit_cast(short8, BUF[jj * 4 + k]);           \
          qp0 = __builtin_amdgcn_mfma_f32_16x16x32_bf16(af[0][k], bfk, qp0, 0, 0, 0); \
          qp1 = __builtin_amdgcn_mfma_f32_16x16x32_bf16(af[1][k], bfk, qp1, 0, 0, 0); \
        }                                                                     \
        _Pragma("unroll")                                                     \
        for (int r = 0; r < 4; ++r) {                                         \
          oacc[0][jj][r] += fast_sqrt(fmaxf(qp0[r], 0.0f));                   \
          oacc[1][jj][r] += fast_sqrt(fmaxf(qp1[r], 0.0f));                   \
        }                                                                     \
      }                                                                       \
    }

  LOAD_B(bufX, 0)
  #pragma unroll 1
  for (int i = 0; i < NB; i += 2) {
    LOAD_B(bufY, i + 1)                 // in flight across X's compute
    COMPUTE_B(bufX, i)
    LOAD_B(bufX, (i + 2) & (NB - 1))    // wraps to b=0 on last iter (harmless)
    COMPUTE_B(bufY, i + 1)
  }
  #undef LOAD_B
  #undef COMPUTE_B

  // --- store: row = q0 + mt2*16 + quad*4 + r, col = (2w+jj)*16 + l15 ---
  #pragma unroll
  for (int mt2 = 0; mt2 < 2; ++mt2)
    #pragma unroll
    for (int jj = 0; jj < 2; ++jj) {
      int col = (w * 2 + jj) * 16 + l15;
      #pragma unroll
      for (int r = 0; r < 4; ++r) {
        int row = q0 + mt2 * 16 + quad * 4 + r;
        out[(size_t)row * NCLS + col] = -oacc[mt2][jj][r];
      }
    }
}

extern "C" void kernel_launch(void* const* d_in, const int* in_sizes, int n_in,
                              void* d_out, int out_size, void* d_ws, size_t ws_size,
                              hipStream_t stream) {
  const float* sup   = (const float*)d_in[0];   // [4096,128] f32
  // d_in[1] = support_labels (unused: sorted/balanced by construction)
  const float* query = (const float*)d_in[2];   // [65536,128] f32
  const int*   bidx  = (const int*)d_in[3];     // [8,128,32] i32
  float* out = (float*)d_out;                   // [65536,128] f32

  unsigned short* pfrag = (unsigned short*)d_ws;              // 256 KB bf16 frags
  float* p2 = (float*)((char*)d_ws + (size_t)NB * NCLS * DIM * 2); // 4 KB

  proto_kernel<<<NB * NCLS, 128, 0, stream>>>(sup, bidx, pfrag, p2);
  dist_kernel<<<NQ / 32, 256, 0, stream>>>(query, (const uint4*)pfrag, p2, out);
}

// Round 6
// 112.927 us; speedup vs baseline: 1.4702x; 1.0734x over previous
//
#include <hip/hip_runtime.h>
#include <hip/hip_bf16.h>

// PrototypicalNetwork: out[q,c] = -1/8 * sum_b sqrt(max(q2[q] + p2[b,c] - 2*qp[b,q,c], 0))
// bf16 MFMA 16x16x32 for qp GEMM (M=65536, N=1024, K=128).
// R6 = R5 (32x128 blocks, ping-pong b-loop, algebra folded into MFMA C-init)
//  + A-frag conversion deduplicated 4x: each wave converts 8 rows, staged in
//    LDS (slot stride padded to 520 shorts -> <=2-way write conflicts = free),
//  + hardware packed bf16 cvt (v_cvt_pk_bf16_f32 via __float22bfloat162_rn).

#define DIM   128
#define NCLS  128
#define SHOTS 32
#define NB    8
#define NQ    65536

using short8 = __attribute__((ext_vector_type(8))) short;
using f32x4  = __attribute__((ext_vector_type(4))) float;

__device__ __forceinline__ unsigned short f2bf(float x) {
  union { float f; unsigned u; } v; v.f = x;
  unsigned r = v.u + 0x7fffu + ((v.u >> 16) & 1u);   // RNE
  return (unsigned short)(r >> 16);
}

__device__ __forceinline__ short8 pack8_bf16(float4 a, float4 b) {
  // v_cvt_pk_bf16_f32 on gfx950 (RNE), 4 insts for 8 elements
  __hip_bfloat162 p0 = __float22bfloat162_rn(make_float2(a.x, a.y));
  __hip_bfloat162 p1 = __float22bfloat162_rn(make_float2(a.z, a.w));
  __hip_bfloat162 p2 = __float22bfloat162_rn(make_float2(b.x, b.y));
  __hip_bfloat162 p3 = __float22bfloat162_rn(make_float2(b.z, b.w));
  union { __hip_bfloat162 h[4]; short8 s; } u;
  u.h[0] = p0; u.h[1] = p1; u.h[2] = p2; u.h[3] = p3;
  return u.s;
}

__device__ __forceinline__ float fast_sqrt(float x) {
#if __has_builtin(__builtin_amdgcn_sqrtf)
  return __builtin_amdgcn_sqrtf(x);   // raw v_sqrt_f32 (never IEEE sqrtf here — R3 regression)
#else
  return sqrtf(x);
#endif
}

// ---------------------------------------------------------------------------
// Kernel 1: bootstrap-mean protos -> bf16(-proto/32) in MFMA B-frag-major
// layout, plus p2[b,c] = |proto|^2 / 64 (fp32).
// B-frag layout (16x16x32): lane holds B[n=lane&15][k=(lane>>4)*8+j].
// Slot = (b*8+ct)*4+kiter; one slot = 64 lanes * 16 B = 1 KB contiguous.
// ---------------------------------------------------------------------------
__global__ __launch_bounds__(128) void proto_kernel(
    const float* __restrict__ sup, const int* __restrict__ bidx,
    unsigned short* __restrict__ pfrag, float* __restrict__ p2) {
  int bc = blockIdx.x;            // b*128 + c
  int c  = bc & (NCLS - 1);
  int d  = threadIdx.x;           // 0..127 = feature dim
  __shared__ int   sidx[SHOTS];
  __shared__ float wsum[2];
  if (d < SHOTS) sidx[d] = bidx[bc * SHOTS + d];
  __syncthreads();
  float acc = 0.f;
  const float* base = sup + c * SHOTS * DIM + d;
  #pragma unroll
  for (int s = 0; s < SHOTS; ++s) acc += base[sidx[s] * DIM];
  float proto = acc * (1.0f / 32.0f);

  int b     = bc >> 7;
  int ct    = c >> 4, l15c = c & 15;
  int kiter = d >> 5, quad = (d >> 3) & 3, j = d & 7;
  int lane  = l15c + (quad << 4);
  int slot  = (b * 8 + ct) * 4 + kiter;
  pfrag[slot * 512 + lane * 8 + j] = f2bf(proto * -0.03125f);  // -proto/32

  float sq = proto * proto;
  #pragma unroll
  for (int off = 32; off > 0; off >>= 1) sq += __shfl_down(sq, off, 64);
  if ((d & 63) == 0) wsum[d >> 6] = sq;
  __syncthreads();
  if (d == 0) p2[bc] = (wsum[0] + wsum[1]) * (1.0f / 64.0f);
}

// ---------------------------------------------------------------------------
// Kernel 2: block = 32 query rows x 128 classes, 4 waves, grid 2048.
// Stage: wave w converts rows [8w, 8w+8) to A-frag layout in LDS (1x cvt per
// block instead of 4x). Then each wave reads all 8 A-frags (2mt x 4k) and runs
// the ping-pong b-loop over its 2 c-tiles. One barrier total.
// ---------------------------------------------------------------------------
#define SLOT_STRIDE 520   // 512 shorts payload + 8 pad -> slot base moves 4 banks

__global__ __launch_bounds__(256) void dist_kernel(
    const float* __restrict__ q, const uint4* __restrict__ pfrag,
    const float* __restrict__ p2, float* __restrict__ out) {
  int tid  = threadIdx.x;
  int w    = tid >> 6, lane = tid & 63;
  int l15  = lane & 15, quad = lane >> 4;
  int q0   = blockIdx.x << 5;

  __shared__ unsigned short aflds[8 * SLOT_STRIDE];  // A-frags, slot = mt*4 + i
  __shared__ float q2s[32];                          // |q|^2 per row (unscaled)

  // --- staging: this wave converts rows 8w..8w+7; lane = (row_local, chunk) ---
  // chunk = 16-float slice of D. A-frag target: slot (mt, i=chunk>>1), within
  // slot position p = quad*16 + m, 8 shorts each; this lane covers quads
  // (chunk&1)*2 and (chunk&1)*2+1 of row m.
  {
    int rloc  = w * 8 + (lane >> 3);        // 0..31 local row
    int chunk = lane & 7;
    const float* src = q + (size_t)(q0 + rloc) * DIM + chunk * 16;
    float4 x0 = *reinterpret_cast<const float4*>(src);
    float4 x1 = *reinterpret_cast<const float4*>(src + 4);
    float4 x2 = *reinterpret_cast<const float4*>(src + 8);
    float4 x3 = *reinterpret_cast<const float4*>(src + 12);
    float s = x0.x*x0.x + x0.y*x0.y + x0.z*x0.z + x0.w*x0.w
            + x1.x*x1.x + x1.y*x1.y + x1.z*x1.z + x1.w*x1.w
            + x2.x*x2.x + x2.y*x2.y + x2.z*x2.z + x2.w*x2.w
            + x3.x*x3.x + x3.y*x3.y + x3.z*x3.z + x3.w*x3.w;
    s += __shfl_down(s, 4, 8);              // reduce over the row's 8 chunks
    s += __shfl_down(s, 2, 8);
    s += __shfl_down(s, 1, 8);
    if (chunk == 0) q2s[rloc] = s;

    int mt = rloc >> 4, m = rloc & 15, i = chunk >> 1, h = chunk & 1;
    unsigned short* base = &aflds[(mt * 4 + i) * SLOT_STRIDE];
    *reinterpret_cast<short8*>(&base[((h * 2 + 0) * 16 + m) * 8]) = pack8_bf16(x0, x1);
    *reinterpret_cast<short8*>(&base[((h * 2 + 1) * 16 + m) * 8]) = pack8_bf16(x2, x3);
  }
  __syncthreads();

  // --- every wave pulls all 8 A-frags + q2' from LDS ---
  short8 af[2][4];
  #pragma unroll
  for (int mt = 0; mt < 2; ++mt)
    #pragma unroll
    for (int k = 0; k < 4; ++k)
      af[mt][k] = *reinterpret_cast<const short8*>(
          &aflds[(mt * 4 + k) * SLOT_STRIDE + lane * 8]);

  f32x4 q2r[2];                    // q2' for C/D row quad*4+r of each m-tile
  #pragma unroll
  for (int mt = 0; mt < 2; ++mt)
    #pragma unroll
    for (int r = 0; r < 4; ++r)
      q2r[mt][r] = q2s[mt * 16 + quad * 4 + r] * (1.0f / 64.0f);

  // p2' hoisted for this wave's two c-tiles, all b (16 L2-hot dwords)
  float p2v[NB][2];
  #pragma unroll
  for (int b = 0; b < NB; ++b)
    #pragma unroll
    for (int jj = 0; jj < 2; ++jj)
      p2v[b][jj] = p2[b * NCLS + (w * 2 + jj) * 16 + l15];

  f32x4 oacc[2][2];
  #pragma unroll
  for (int i = 0; i < 2; ++i)
    #pragma unroll
    for (int jj = 0; jj < 2; ++jj)
      oacc[i][jj] = (f32x4){0.f, 0.f, 0.f, 0.f};

  // --- b-loop: X/Y ping-pong, 8 frag loads in flight across each compute ---
  uint4 bufX[8], bufY[8];

  #define LOAD_B(BUF, B)                                                      \
    {                                                                         \
      _Pragma("unroll")                                                       \
      for (int jj = 0; jj < 2; ++jj) {                                        \
        int ct = w * 2 + jj;                                                  \
        const uint4* bp = pfrag + (size_t)(((B) * 8 + ct) * 4) * 64 + lane;   \
        _Pragma("unroll")                                                     \
        for (int k = 0; k < 4; ++k) BUF[jj * 4 + k] = bp[k * 64];             \
      }                                                                       \
    }

  #define COMPUTE_B(BUF, B)                                                   \
    {                                                                         \
      _Pragma("unroll")                                                       \
      for (int jj = 0; jj < 2; ++jj) {                                        \
        f32x4 qp0, qp1;                                                       \
        _Pragma("unroll")                                                     \
        for (int r = 0; r < 4; ++r) {                                         \
          qp0[r] = q2r[0][r] + p2v[B][jj];                                    \
          qp1[r] = q2r[1][r] + p2v[B][jj];                                    \
        }                                                                     \
        _Pragma("unroll")                                                     \
        for (int k = 0; k < 4; ++k) {                                         \
          short8 bfk = __builtin_bit_cast(short8, BUF[jj * 4 + k]);           \
          qp0 = __builtin_amdgcn_mfma_f32_16x16x32_bf16(af[0][k], bfk, qp0, 0, 0, 0); \
          qp1 = __builtin_amdgcn_mfma_f32_16x16x32_bf16(af[1][k], bfk, qp1, 0, 0, 0); \
        }                                                                     \
        _Pragma("unroll")                                                     \
        for (int r = 0; r < 4; ++r) {                                         \
          oacc[0][jj][r] += fast_sqrt(fmaxf(qp0[r], 0.0f));                   \
          oacc[1][jj][r] += fast_sqrt(fmaxf(qp1[r], 0.0f));                   \
        }                                                                     \
      }                                                                       \
    }

  LOAD_B(bufX, 0)
  #pragma unroll 1
  for (int i = 0; i < NB; i += 2) {
    LOAD_B(bufY, i + 1)                 // in flight across X's compute
    COMPUTE_B(bufX, i)
    LOAD_B(bufX, (i + 2) & (NB - 1))    // wraps to b=0 on last iter (harmless)
    COMPUTE_B(bufY, i + 1)
  }
  #undef LOAD_B
  #undef COMPUTE_B

  // --- store: row = q0 + mt2*16 + quad*4 + r, col = (2w+jj)*16 + l15 ---
  #pragma unroll
  for (int mt2 = 0; mt2 < 2; ++mt2)
    #pragma unroll
    for (int jj = 0; jj < 2; ++jj) {
      int col = (w * 2 + jj) * 16 + l15;
      #pragma unroll
      for (int r = 0; r < 4; ++r) {
        int row = q0 + mt2 * 16 + quad * 4 + r;
        out[(size_t)row * NCLS + col] = -oacc[mt2][jj][r];
      }
    }
}

extern "C" void kernel_launch(void* const* d_in, const int* in_sizes, int n_in,
                              void* d_out, int out_size, void* d_ws, size_t ws_size,
                              hipStream_t stream) {
  const float* sup   = (const float*)d_in[0];   // [4096,128] f32
  // d_in[1] = support_labels (unused: sorted/balanced by construction)
  const float* query = (const float*)d_in[2];   // [65536,128] f32
  const int*   bidx  = (const int*)d_in[3];     // [8,128,32] i32
  float* out = (float*)d_out;                   // [65536,128] f32

  unsigned short* pfrag = (unsigned short*)d_ws;              // 256 KB bf16 frags
  float* p2 = (float*)((char*)d_ws + (size_t)NB * NCLS * DIM * 2); // 4 KB

  proto_kernel<<<NB * NCLS, 128, 0, stream>>>(sup, bidx, pfrag, p2);
  dist_kernel<<<NQ / 32, 256, 0, stream>>>(query, (const uint4*)pfrag, p2, out);
}